// Round 6
// baseline (317.037 us; speedup 1.0000x reference)
//
#include <hip/hip_runtime.h>
#include <math.h>

#define H 8
#define C 32
#define HC 256      // H*C
#define FE 16
#define FIN 128
#define NEG_SLOPE 0.2f

typedef __attribute__((ext_vector_type(8))) short bf16x8;
typedef __attribute__((ext_vector_type(4))) float f32x4;

__device__ __forceinline__ unsigned short f2bf(float f) {
  unsigned int u = __float_as_uint(f);
  unsigned int lsb = (u >> 16) & 1u;
  u += 0x7fffu + lsb;               // round-to-nearest-even
  return (unsigned short)(u >> 16);
}
__device__ __forceinline__ float bf2f(unsigned short s) {
  return __uint_as_float(((unsigned int)s) << 16);
}

// split 8 fp32 into hi (truncated bf16) + lo (RNE bf16 of residual)
__device__ __forceinline__ void split8(const float* v, bf16x8& hi, bf16x8& lo) {
#pragma unroll
  for (int i = 0; i < 8; ++i) {
    unsigned int u = __float_as_uint(v[i]);
    unsigned int hu = u & 0xffff0000u;
    float r = v[i] - __uint_as_float(hu);
    hi[i] = (short)(hu >> 16);
    lo[i] = (short)f2bf(r);
  }
}

// ---------------- xh^T = W @ x^T via MFMA split-bf16 (3 passes, fp32-grade accuracy) ----------------
__global__ __launch_bounds__(256) void k_xh(const float* __restrict__ x,
                                            const unsigned short* __restrict__ Whi,
                                            const unsigned short* __restrict__ Wlo,
                                            const float* __restrict__ att_src,
                                            const float* __restrict__ att_dst,
                                            unsigned short* __restrict__ xhb,
                                            float* __restrict__ a_src,
                                            float* __restrict__ a_dst, int N) {
  int t = threadIdx.x;
  int w = t >> 6, lane = t & 63;
  int n15 = lane & 15, q = lane >> 4;
  int nodeBase = blockIdx.x * 128 + w * 32;      // + nt*16 + n15
  int chBase = blockIdx.y * 128;                 // + mt*16 + (row idx)

  f32x4 acc[8][2];
#pragma unroll
  for (int mt = 0; mt < 8; ++mt)
#pragma unroll
    for (int nt = 0; nt < 2; ++nt) acc[mt][nt] = (f32x4)(0.f);

  for (int ks = 0; ks < 4; ++ks) {
    int kOff = ks * 32 + q * 8;
    bf16x8 Bhi[2], Blo[2];
#pragma unroll
    for (int nt = 0; nt < 2; ++nt) {
      int node = nodeBase + nt * 16 + n15;
      int rn = (node < N) ? node : (N - 1);
      const float* px = &x[(size_t)rn * FIN + kOff];
      float vb[8];
      *(float4*)&vb[0] = *(const float4*)px;
      *(float4*)&vb[4] = *(const float4*)(px + 4);
      split8(vb, Bhi[nt], Blo[nt]);
    }
#pragma unroll
    for (int mt = 0; mt < 8; ++mt) {
      int widx = ((chBase + mt * 16 + n15) << 7) + kOff;
      bf16x8 Ahi = *(const bf16x8*)&Whi[widx];
      bf16x8 Alo = *(const bf16x8*)&Wlo[widx];
#pragma unroll
      for (int nt = 0; nt < 2; ++nt) {
        acc[mt][nt] = __builtin_amdgcn_mfma_f32_16x16x32_bf16(Ahi, Bhi[nt], acc[mt][nt], 0, 0, 0);
        acc[mt][nt] = __builtin_amdgcn_mfma_f32_16x16x32_bf16(Ahi, Blo[nt], acc[mt][nt], 0, 0, 0);
        acc[mt][nt] = __builtin_amdgcn_mfma_f32_16x16x32_bf16(Alo, Bhi[nt], acc[mt][nt], 0, 0, 0);
      }
    }
  }

  // Epilogue. C/D layout: col(lane&15)=node, row=q*4+reg = channel within tile.
  float ps[2][4] = {{0.f,0.f,0.f,0.f},{0.f,0.f,0.f,0.f}};
  float pd[2][4] = {{0.f,0.f,0.f,0.f},{0.f,0.f,0.f,0.f}};
#pragma unroll
  for (int mt = 0; mt < 8; ++mt) {
    int hl = mt >> 1;
#pragma unroll
    for (int r = 0; r < 4; ++r) {
      int ch = chBase + mt * 16 + q * 4 + r;
      float as_c = att_src[ch], ad_c = att_dst[ch];
#pragma unroll
      for (int nt = 0; nt < 2; ++nt) {
        float val = acc[mt][nt][r];
        ps[nt][hl] = fmaf(val, as_c, ps[nt][hl]);
        pd[nt][hl] = fmaf(val, ad_c, pd[nt][hl]);
      }
    }
#pragma unroll
    for (int nt = 0; nt < 2; ++nt) {
      int node = nodeBase + nt * 16 + n15;
      if (node < N) {
        ushort4 us;
        us.x = f2bf(acc[mt][nt][0]); us.y = f2bf(acc[mt][nt][1]);
        us.z = f2bf(acc[mt][nt][2]); us.w = f2bf(acc[mt][nt][3]);
        *(ushort4*)&xhb[(size_t)node * HC + chBase + mt * 16 + q * 4] = us;
      }
    }
  }
#pragma unroll
  for (int nt = 0; nt < 2; ++nt)
#pragma unroll
    for (int hl = 0; hl < 4; ++hl) {
      ps[nt][hl] += __shfl_xor(ps[nt][hl], 16, 64);
      ps[nt][hl] += __shfl_xor(ps[nt][hl], 32, 64);
      pd[nt][hl] += __shfl_xor(pd[nt][hl], 16, 64);
      pd[nt][hl] += __shfl_xor(pd[nt][hl], 32, 64);
    }
  if (q == 0) {
#pragma unroll
    for (int nt = 0; nt < 2; ++nt) {
      int node = nodeBase + nt * 16 + n15;
      if (node < N) {
        *(float4*)&a_src[node * H + blockIdx.y * 4] = make_float4(ps[nt][0], ps[nt][1], ps[nt][2], ps[nt][3]);
        *(float4*)&a_dst[node * H + blockIdx.y * 4] = make_float4(pd[nt][0], pd[nt][1], pd[nt][2], pd[nt][3]);
      }
    }
  }
}

// ---------------- degree histogram + rank; also splits W into bf16 hi/lo (fused one-off) ----------------
__global__ __launch_bounds__(256) void k_deg(const int* __restrict__ ei,
                                             int* __restrict__ deg,
                                             int* __restrict__ rank,
                                             const float* __restrict__ W,
                                             unsigned short* __restrict__ Whi,
                                             unsigned short* __restrict__ Wlo, int E) {
  int e = blockIdx.x * 256 + threadIdx.x;
  if (e < HC * FIN) {
    float v = W[e];
    unsigned int u = __float_as_uint(v);
    unsigned int hu = u & 0xffff0000u;
    Whi[e] = (unsigned short)(hu >> 16);
    Wlo[e] = f2bf(v - __uint_as_float(hu));
  }
  if (e < E) rank[e] = atomicAdd(&deg[ei[E + e]], 1);
}

// ---------------- hierarchical scan ----------------
__global__ __launch_bounds__(256) void k_scan1(const int* __restrict__ deg,
                                               int* __restrict__ bsum, int N) {
  int t = threadIdx.x;
  int i = blockIdx.x * 256 + t;
  int v = (i < N) ? deg[i] : 0;
#pragma unroll
  for (int m = 1; m < 64; m <<= 1) v += __shfl_xor(v, m, 64);
  __shared__ int wsum[4];
  if ((t & 63) == 0) wsum[t >> 6] = v;
  __syncthreads();
  if (t == 0) bsum[blockIdx.x] = wsum[0] + wsum[1] + wsum[2] + wsum[3];
}

__global__ __launch_bounds__(256) void k_scan2(const int* __restrict__ bsum,
                                               int* __restrict__ boff, int nb) {
  __shared__ int buf[256];
  int t = threadIdx.x;
  int v = (t < nb) ? bsum[t] : 0;
  buf[t] = v;
  __syncthreads();
  for (int off = 1; off < 256; off <<= 1) {
    int y = (t >= off) ? buf[t - off] : 0;
    __syncthreads();
    buf[t] += y;
    __syncthreads();
  }
  if (t < nb) boff[t] = buf[t] - v;   // exclusive
}

__global__ __launch_bounds__(256) void k_scan3(const int* __restrict__ deg,
                                               const int* __restrict__ boff,
                                               int* __restrict__ rowptr, int N, int E) {
  __shared__ int buf[256];
  int t = threadIdx.x;
  int i = blockIdx.x * 256 + t;
  int v = (i < N) ? deg[i] : 0;
  buf[t] = v;
  __syncthreads();
  for (int off = 1; off < 256; off <<= 1) {
    int y = (t >= off) ? buf[t - off] : 0;
    __syncthreads();
    buf[t] += y;
    __syncthreads();
  }
  if (i < N) rowptr[i] = boff[blockIdx.x] + buf[t] - v;
  if (i == 0) rowptr[N] = E;
}

// ---------------- per-edge: a_edge = ea @ M -> 32B CSR record {bf16 ae[8], int src} ----------------
__global__ __launch_bounds__(256) void k_edge_scatter(const int* __restrict__ ei,
                                                      const float* __restrict__ ea,
                                                      const float* __restrict__ W_edge,
                                                      const float* __restrict__ att_edge,
                                                      const int* __restrict__ rowptr,
                                                      const int* __restrict__ rank,
                                                      unsigned short* __restrict__ recs, int E) {
  __shared__ float Ms[FE * H];
  int t = threadIdx.x;
  if (t < FE * H) {          // M[f][h] = sum_c W_edge[(h*C+c)*FE+f] * att_edge[h*C+c]
    int f = t >> 3, h = t & 7;
    float acc = 0.f;
#pragma unroll
    for (int c = 0; c < C; ++c)
      acc += W_edge[(h * C + c) * FE + f] * att_edge[h * C + c];
    Ms[f * H + h] = acc;
  }
  __syncthreads();
  int e = blockIdx.x * 256 + t;
  if (e >= E) return;
  int s = ei[e], d = ei[E + e];
  const float4* p = (const float4*)&ea[(size_t)e * FE];
  float4 v0 = p[0], v1 = p[1], v2 = p[2], v3 = p[3];
  float eav[FE] = {v0.x, v0.y, v0.z, v0.w, v1.x, v1.y, v1.z, v1.w,
                   v2.x, v2.y, v2.z, v2.w, v3.x, v3.y, v3.z, v3.w};
  float o[H];
#pragma unroll
  for (int h = 0; h < H; ++h) {
    float acc = 0.f;
#pragma unroll
    for (int f = 0; f < FE; ++f) acc += eav[f] * Ms[f * H + h];
    o[h] = acc;
  }
  int pos = rowptr[d] + rank[e];
  uint4 pk;
  pk.x = (unsigned int)f2bf(o[0]) | ((unsigned int)f2bf(o[1]) << 16);
  pk.y = (unsigned int)f2bf(o[2]) | ((unsigned int)f2bf(o[3]) << 16);
  pk.z = (unsigned int)f2bf(o[4]) | ((unsigned int)f2bf(o[5]) << 16);
  pk.w = (unsigned int)f2bf(o[6]) | ((unsigned int)f2bf(o[7]) << 16);
  uint4 hv; hv.x = (unsigned int)s; hv.y = 0; hv.z = 0; hv.w = 0;
  unsigned short* rp = &recs[(size_t)pos * 16];
  *(uint4*)rp = pk;
  *(uint4*)(rp + 8) = hv;
}

// ---------------- wave-per-node: batched-load softmax + 8-deep pipelined gather ----------------
__global__ __launch_bounds__(256) void k_node(const unsigned short* __restrict__ xhb,
                                              const float* __restrict__ a_src,
                                              const float* __restrict__ a_dst,
                                              const unsigned short* __restrict__ recs,
                                              const int* __restrict__ rowptr,
                                              const float* __restrict__ bias,
                                              float* __restrict__ out, int N) {
  __shared__ float wlds[4][512];   // [wave][j*8+h], j<64
  __shared__ int   slds[4][64];
  int wv = threadIdx.x >> 6;
  int lane = threadIdx.x & 63;
  int n = blockIdx.x * 4 + wv;
  if (n >= N) return;
  int start = rowptr[n];
  int deg = rowptr[n + 1] - start;
  int jmax = (deg < 64) ? deg : 64;
  int h = lane & 7, esub = lane >> 3;
  float adst = a_dst[n * H + h];
  float asrc = a_src[n * H + h];

  // ---- phase 1a: batch record loads (16 independent loads in flight) ----
  float ae[8]; int sr[8];
#pragma unroll
  for (int it = 0; it < 8; ++it) {
    int j = it * 8 + esub;
    ae[it] = 0.f; sr[it] = 0;
    if (j < jmax) {
      const unsigned short* rp = &recs[(size_t)(start + j) * 16];
      ae[it] = bf2f(rp[h]);
      sr[it] = *(const int*)(rp + 8);
    }
  }
  // ---- phase 1b: batch a_src gathers (8 in flight) + stash src to LDS ----
  float asg[8];
#pragma unroll
  for (int it = 0; it < 8; ++it) {
    int j = it * 8 + esub;
    asg[it] = (j < jmax) ? a_src[sr[it] * H + h] : 0.f;
  }
  if (h == 0) {
#pragma unroll
    for (int it = 0; it < 8; ++it) {
      int j = it * 8 + esub;
      if (j < jmax) slds[wv][j] = sr[it];
    }
  }
  // ---- phase 1c: alphas in registers, per-lane max + raw-ae sum ----
  float al[8];
  float pmax = -1e30f, psum = 0.f;
#pragma unroll
  for (int it = 0; it < 8; ++it) {
    int j = it * 8 + esub;
    float a = -1e30f;
    if (j < jmax) {
      psum += ae[it];
      a = asg[it] + adst + ae[it];
      a = (a >= 0.f) ? a : NEG_SLOPE * a;
      pmax = fmaxf(pmax, a);
    }
    al[it] = a;
  }
  for (int j0 = 64; j0 < deg; j0 += 8) {   // overflow deg>64 (rare)
    int j = j0 + esub;
    if (j < deg) {
      const unsigned short* rp = &recs[(size_t)(start + j) * 16];
      float aev = bf2f(rp[h]);
      int src = *(const int*)(rp + 8);
      psum += aev;
      float a = a_src[src * H + h] + adst + aev;
      a = (a >= 0.f) ? a : NEG_SLOPE * a;
      pmax = fmaxf(pmax, a);
    }
  }
#pragma unroll
  for (int m = 8; m <= 32; m <<= 1) {
    pmax = fmaxf(pmax, __shfl_xor(pmax, m, 64));
    psum += __shfl_xor(psum, m, 64);
  }
  float aself = asrc + adst + psum / fmaxf((float)deg, 1.f);
  aself = (aself >= 0.f) ? aself : NEG_SLOPE * aself;
  float amax = fmaxf(pmax, aself);

  // ---- phase 2: unnormalized weights -> LDS, per-head denom ----
  float den = 0.f;
#pragma unroll
  for (int it = 0; it < 8; ++it) {
    int j = it * 8 + esub;
    if (j < jmax) {
      float wj = __expf(al[it] - amax);
      den += wj;
      wlds[wv][j * 8 + h] = wj;
    }
  }
  for (int j0 = 64; j0 < deg; j0 += 8) {   // overflow
    int j = j0 + esub;
    if (j < deg) {
      const unsigned short* rp = &recs[(size_t)(start + j) * 16];
      float aev = bf2f(rp[h]);
      int src = *(const int*)(rp + 8);
      float a = a_src[src * H + h] + adst + aev;
      a = (a >= 0.f) ? a : NEG_SLOPE * a;
      den += __expf(a - amax);
    }
  }
#pragma unroll
  for (int m = 8; m <= 32; m <<= 1) den += __shfl_xor(den, m, 64);
  float wself = __expf(aself - amax);
  float inv = 1.f / (den + wself);

  // ---- phase 3: 8-deep double-buffered gather; lane -> channels lane*4..+3, head hc ----
  int hc = lane >> 3;
  float inv_c  = __shfl(inv, hc, 64);
  float ws_c   = __shfl(wself, hc, 64);
  float amax_c = __shfl(amax, hc, 64);
  float adst_c = __shfl(adst, hc, 64);
  float accx, accy, accz, accw;
  {
    uint2 u = ((const uint2*)(xhb + (((size_t)n) << 8)))[lane];
    accx = ws_c * __uint_as_float(u.x << 16);
    accy = ws_c * __uint_as_float(u.x & 0xffff0000u);
    accz = ws_c * __uint_as_float(u.y << 16);
    accw = ws_c * __uint_as_float(u.y & 0xffff0000u);
  }
  uint2 va[8]; float wa[8];
#pragma unroll
  for (int k = 0; k < 8; ++k) {
    va[k] = make_uint2(0u, 0u); wa[k] = 0.f;
    if (k < jmax) {
      wa[k] = wlds[wv][k * 8 + hc];
      va[k] = ((const uint2*)(xhb + (((size_t)slds[wv][k]) << 8)))[lane];
    }
  }
  for (int j0 = 0; j0 < jmax; j0 += 8) {
    uint2 vb[8]; float wb[8];
#pragma unroll
    for (int k = 0; k < 8; ++k) {
      int jn = j0 + 8 + k;
      vb[k] = make_uint2(0u, 0u); wb[k] = 0.f;
      if (jn < jmax) {
        wb[k] = wlds[wv][jn * 8 + hc];
        vb[k] = ((const uint2*)(xhb + (((size_t)slds[wv][jn]) << 8)))[lane];
      }
    }
#pragma unroll
    for (int k = 0; k < 8; ++k) {
      uint2 v = va[k]; float wj = wa[k];
      accx = fmaf(__uint_as_float(v.x << 16), wj, accx);
      accy = fmaf(__uint_as_float(v.x & 0xffff0000u), wj, accy);
      accz = fmaf(__uint_as_float(v.y << 16), wj, accz);
      accw = fmaf(__uint_as_float(v.y & 0xffff0000u), wj, accw);
      va[k] = vb[k]; wa[k] = wb[k];
    }
  }
  for (int j = 64; j < deg; ++j) {       // overflow: recompute weight
    const unsigned short* rp = &recs[(size_t)(start + j) * 16];
    float aev = bf2f(rp[hc]);
    int src = *(const int*)(rp + 8);
    float a = a_src[src * H + hc] + adst_c + aev;
    a = (a >= 0.f) ? a : NEG_SLOPE * a;
    float wj = __expf(a - amax_c);
    uint2 v = ((const uint2*)(xhb + (((size_t)src) << 8)))[lane];
    accx = fmaf(__uint_as_float(v.x << 16), wj, accx);
    accy = fmaf(__uint_as_float(v.x & 0xffff0000u), wj, accy);
    accz = fmaf(__uint_as_float(v.y << 16), wj, accz);
    accw = fmaf(__uint_as_float(v.y & 0xffff0000u), wj, accw);
  }
  accx *= inv_c; accy *= inv_c; accz *= inv_c; accw *= inv_c;

  // head mean across hc (xor 8,16,32)
#pragma unroll
  for (int m = 8; m <= 32; m <<= 1) {
    accx += __shfl_xor(accx, m, 64);
    accy += __shfl_xor(accy, m, 64);
    accz += __shfl_xor(accz, m, 64);
    accw += __shfl_xor(accw, m, 64);
  }
  if (lane < 8) {
    float4 b = ((const float4*)bias)[lane];
    float4 o;
    o.x = accx * 0.125f + b.x;
    o.y = accy * 0.125f + b.y;
    o.z = accz * 0.125f + b.z;
    o.w = accw * 0.125f + b.w;
    ((float4*)&out[(size_t)n * C])[lane] = o;
  }
}

extern "C" void kernel_launch(void* const* d_in, const int* in_sizes, int n_in,
                              void* d_out, int out_size, void* d_ws, size_t ws_size,
                              hipStream_t stream) {
  const float* x        = (const float*)d_in[0];
  const int*   ei       = (const int*)d_in[1];
  const float* ea       = (const float*)d_in[2];
  const float* W        = (const float*)d_in[3];
  const float* W_edge   = (const float*)d_in[4];
  const float* att_src  = (const float*)d_in[5];
  const float* att_dst  = (const float*)d_in[6];
  const float* att_edge = (const float*)d_in[7];
  const float* bias     = (const float*)d_in[8];
  float* out = (float*)d_out;

  int N = in_sizes[0] / FIN;
  int E = in_sizes[1] / 2;
  int nb = (N + 255) / 256;

  char* ws = (char*)d_ws;
  auto take = [&](size_t bytes) {
    char* p = ws;
    ws += (bytes + 255) & ~(size_t)255;
    return p;
  };
  unsigned short* xhb    = (unsigned short*)take((size_t)N * HC * 2);
  float*          a_src  = (float*)take((size_t)N * H * 4);
  float*          a_dst  = (float*)take((size_t)N * H * 4);
  unsigned short* recs   = (unsigned short*)take((size_t)E * 32);
  unsigned short* Whi    = (unsigned short*)take((size_t)HC * FIN * 2);
  unsigned short* Wlo    = (unsigned short*)take((size_t)HC * FIN * 2);
  int*            deg    = (int*)take((size_t)N * 4);
  int*            rowptr = (int*)take((size_t)(N + 1) * 4);
  int*            rank   = (int*)take((size_t)E * 4);
  int*            bsum   = (int*)take((size_t)nb * 4);
  int*            boff   = (int*)take((size_t)nb * 4);

  hipMemsetAsync(deg, 0, (size_t)N * 4, stream);
  k_deg<<<(E + 255) / 256, 256, 0, stream>>>(ei, deg, rank, W, Whi, Wlo, E);
  k_xh<<<dim3((N + 127) / 128, 2), 256, 0, stream>>>(x, Whi, Wlo, att_src, att_dst, xhb, a_src, a_dst, N);
  k_scan1<<<nb, 256, 0, stream>>>(deg, bsum, N);
  k_scan2<<<1, 256, 0, stream>>>(bsum, boff, nb);
  k_scan3<<<nb, 256, 0, stream>>>(deg, boff, rowptr, N, E);
  k_edge_scatter<<<(E + 255) / 256, 256, 0, stream>>>(ei, ea, W_edge, att_edge, rowptr, rank, recs, E);
  k_node<<<(N + 3) / 4, 256, 0, stream>>>(xhb, a_src, a_dst, recs, rowptr, bias, out, N);
}

// Round 7
// 301.879 us; speedup vs baseline: 1.0502x; 1.0502x over previous
//
#include <hip/hip_runtime.h>
#include <math.h>

#define H 8
#define C 32
#define HC 256      // H*C
#define FE 16
#define FIN 128
#define NEG_SLOPE 0.2f

typedef __attribute__((ext_vector_type(8))) short bf16x8;
typedef __attribute__((ext_vector_type(4))) float f32x4;

__device__ __forceinline__ unsigned short f2bf(float f) {
  unsigned int u = __float_as_uint(f);
  unsigned int lsb = (u >> 16) & 1u;
  u += 0x7fffu + lsb;               // round-to-nearest-even
  return (unsigned short)(u >> 16);
}
__device__ __forceinline__ float bf2f(unsigned short s) {
  return __uint_as_float(((unsigned int)s) << 16);
}

// split 8 fp32 into hi (truncated bf16) + lo (RNE bf16 of residual)
__device__ __forceinline__ void split8(const float* v, bf16x8& hi, bf16x8& lo) {
#pragma unroll
  for (int i = 0; i < 8; ++i) {
    unsigned int u = __float_as_uint(v[i]);
    unsigned int hu = u & 0xffff0000u;
    float r = v[i] - __uint_as_float(hu);
    hi[i] = (short)(hu >> 16);
    lo[i] = (short)f2bf(r);
  }
}

// ---------------- xh^T = W @ x^T via MFMA split-bf16 (3 passes, fp32-grade accuracy) ----------------
__global__ __launch_bounds__(256) void k_xh(const float* __restrict__ x,
                                            const unsigned short* __restrict__ Whi,
                                            const unsigned short* __restrict__ Wlo,
                                            const float* __restrict__ att_src,
                                            const float* __restrict__ att_dst,
                                            unsigned short* __restrict__ xhb,
                                            float* __restrict__ a_src,
                                            float* __restrict__ a_dst, int N) {
  int t = threadIdx.x;
  int w = t >> 6, lane = t & 63;
  int n15 = lane & 15, q = lane >> 4;
  int nodeBase = blockIdx.x * 128 + w * 32;      // + nt*16 + n15
  int chBase = blockIdx.y * 128;                 // + mt*16 + (row idx)

  f32x4 acc[8][2];
#pragma unroll
  for (int mt = 0; mt < 8; ++mt)
#pragma unroll
    for (int nt = 0; nt < 2; ++nt) acc[mt][nt] = (f32x4)(0.f);

  for (int ks = 0; ks < 4; ++ks) {
    int kOff = ks * 32 + q * 8;
    bf16x8 Bhi[2], Blo[2];
#pragma unroll
    for (int nt = 0; nt < 2; ++nt) {
      int node = nodeBase + nt * 16 + n15;
      int rn = (node < N) ? node : (N - 1);
      const float* px = &x[(size_t)rn * FIN + kOff];
      float vb[8];
      *(float4*)&vb[0] = *(const float4*)px;
      *(float4*)&vb[4] = *(const float4*)(px + 4);
      split8(vb, Bhi[nt], Blo[nt]);
    }
#pragma unroll
    for (int mt = 0; mt < 8; ++mt) {
      int widx = ((chBase + mt * 16 + n15) << 7) + kOff;
      bf16x8 Ahi = *(const bf16x8*)&Whi[widx];
      bf16x8 Alo = *(const bf16x8*)&Wlo[widx];
#pragma unroll
      for (int nt = 0; nt < 2; ++nt) {
        acc[mt][nt] = __builtin_amdgcn_mfma_f32_16x16x32_bf16(Ahi, Bhi[nt], acc[mt][nt], 0, 0, 0);
        acc[mt][nt] = __builtin_amdgcn_mfma_f32_16x16x32_bf16(Ahi, Blo[nt], acc[mt][nt], 0, 0, 0);
        acc[mt][nt] = __builtin_amdgcn_mfma_f32_16x16x32_bf16(Alo, Bhi[nt], acc[mt][nt], 0, 0, 0);
      }
    }
  }

  // Epilogue. C/D layout: col(lane&15)=node, row=q*4+reg = channel within tile.
  float ps[2][4] = {{0.f,0.f,0.f,0.f},{0.f,0.f,0.f,0.f}};
  float pd[2][4] = {{0.f,0.f,0.f,0.f},{0.f,0.f,0.f,0.f}};
#pragma unroll
  for (int mt = 0; mt < 8; ++mt) {
    int hl = mt >> 1;
#pragma unroll
    for (int r = 0; r < 4; ++r) {
      int ch = chBase + mt * 16 + q * 4 + r;
      float as_c = att_src[ch], ad_c = att_dst[ch];
#pragma unroll
      for (int nt = 0; nt < 2; ++nt) {
        float val = acc[mt][nt][r];
        ps[nt][hl] = fmaf(val, as_c, ps[nt][hl]);
        pd[nt][hl] = fmaf(val, ad_c, pd[nt][hl]);
      }
    }
#pragma unroll
    for (int nt = 0; nt < 2; ++nt) {
      int node = nodeBase + nt * 16 + n15;
      if (node < N) {
        ushort4 us;
        us.x = f2bf(acc[mt][nt][0]); us.y = f2bf(acc[mt][nt][1]);
        us.z = f2bf(acc[mt][nt][2]); us.w = f2bf(acc[mt][nt][3]);
        *(ushort4*)&xhb[(size_t)node * HC + chBase + mt * 16 + q * 4] = us;
      }
    }
  }
#pragma unroll
  for (int nt = 0; nt < 2; ++nt)
#pragma unroll
    for (int hl = 0; hl < 4; ++hl) {
      ps[nt][hl] += __shfl_xor(ps[nt][hl], 16, 64);
      ps[nt][hl] += __shfl_xor(ps[nt][hl], 32, 64);
      pd[nt][hl] += __shfl_xor(pd[nt][hl], 16, 64);
      pd[nt][hl] += __shfl_xor(pd[nt][hl], 32, 64);
    }
  if (q == 0) {
#pragma unroll
    for (int nt = 0; nt < 2; ++nt) {
      int node = nodeBase + nt * 16 + n15;
      if (node < N) {
        *(float4*)&a_src[node * H + blockIdx.y * 4] = make_float4(ps[nt][0], ps[nt][1], ps[nt][2], ps[nt][3]);
        *(float4*)&a_dst[node * H + blockIdx.y * 4] = make_float4(pd[nt][0], pd[nt][1], pd[nt][2], pd[nt][3]);
      }
    }
  }
}

// ---------------- degree histogram + rank; also splits W into bf16 hi/lo (fused one-off) ----------------
__global__ __launch_bounds__(256) void k_deg(const int* __restrict__ ei,
                                             int* __restrict__ deg,
                                             int* __restrict__ rank,
                                             const float* __restrict__ W,
                                             unsigned short* __restrict__ Whi,
                                             unsigned short* __restrict__ Wlo, int E) {
  int e = blockIdx.x * 256 + threadIdx.x;
  if (e < HC * FIN) {
    float v = W[e];
    unsigned int u = __float_as_uint(v);
    unsigned int hu = u & 0xffff0000u;
    Whi[e] = (unsigned short)(hu >> 16);
    Wlo[e] = f2bf(v - __uint_as_float(hu));
  }
  if (e < E) rank[e] = atomicAdd(&deg[ei[E + e]], 1);
}

// ---------------- scan stage 1: per-block sums ----------------
__global__ __launch_bounds__(256) void k_scan1(const int* __restrict__ deg,
                                               int* __restrict__ bsum, int N) {
  int t = threadIdx.x;
  int i = blockIdx.x * 256 + t;
  int v = (i < N) ? deg[i] : 0;
#pragma unroll
  for (int m = 1; m < 64; m <<= 1) v += __shfl_xor(v, m, 64);
  __shared__ int wsum[4];
  if ((t & 63) == 0) wsum[t >> 6] = v;
  __syncthreads();
  if (t == 0) bsum[blockIdx.x] = wsum[0] + wsum[1] + wsum[2] + wsum[3];
}

// ---------------- scan stage 2+3 fused: every block scans bsum in LDS, then local scan ----------------
__global__ __launch_bounds__(256) void k_scan23(const int* __restrict__ deg,
                                                const int* __restrict__ bsum,
                                                int* __restrict__ rowptr, int N, int E, int nb) {
  __shared__ int sb[256];
  __shared__ int buf[256];
  int t = threadIdx.x;
  sb[t] = (t < nb) ? bsum[t] : 0;
  int i = blockIdx.x * 256 + t;
  int v = (i < N) ? deg[i] : 0;
  buf[t] = v;
  __syncthreads();
  for (int off = 1; off < 256; off <<= 1) {
    int y1 = (t >= off) ? sb[t - off] : 0;
    int y2 = (t >= off) ? buf[t - off] : 0;
    __syncthreads();
    sb[t] += y1;
    buf[t] += y2;
    __syncthreads();
  }
  int bofs = (blockIdx.x == 0) ? 0 : sb[blockIdx.x - 1];
  if (i < N) rowptr[i] = bofs + buf[t] - v;
  if (i == 0) rowptr[N] = E;
}

// ---------------- per-edge: a_edge = ea @ M -> 32B CSR record {bf16 ae[8], int src} ----------------
__global__ __launch_bounds__(256) void k_edge_scatter(const int* __restrict__ ei,
                                                      const float* __restrict__ ea,
                                                      const float* __restrict__ W_edge,
                                                      const float* __restrict__ att_edge,
                                                      const int* __restrict__ rowptr,
                                                      const int* __restrict__ rank,
                                                      unsigned short* __restrict__ recs, int E) {
  __shared__ float Ms[FE * H];
  int t = threadIdx.x;
  if (t < FE * H) {          // M[f][h] = sum_c W_edge[(h*C+c)*FE+f] * att_edge[h*C+c]
    int f = t >> 3, h = t & 7;
    float acc = 0.f;
#pragma unroll
    for (int c = 0; c < C; ++c)
      acc += W_edge[(h * C + c) * FE + f] * att_edge[h * C + c];
    Ms[f * H + h] = acc;
  }
  __syncthreads();
  int e = blockIdx.x * 256 + t;
  if (e >= E) return;
  int s = ei[e], d = ei[E + e];
  const float4* p = (const float4*)&ea[(size_t)e * FE];
  float4 v0 = p[0], v1 = p[1], v2 = p[2], v3 = p[3];
  float eav[FE] = {v0.x, v0.y, v0.z, v0.w, v1.x, v1.y, v1.z, v1.w,
                   v2.x, v2.y, v2.z, v2.w, v3.x, v3.y, v3.z, v3.w};
  float o[H];
#pragma unroll
  for (int h = 0; h < H; ++h) {
    float acc = 0.f;
#pragma unroll
    for (int f = 0; f < FE; ++f) acc += eav[f] * Ms[f * H + h];
    o[h] = acc;
  }
  int pos = rowptr[d] + rank[e];
  uint4 pk;
  pk.x = (unsigned int)f2bf(o[0]) | ((unsigned int)f2bf(o[1]) << 16);
  pk.y = (unsigned int)f2bf(o[2]) | ((unsigned int)f2bf(o[3]) << 16);
  pk.z = (unsigned int)f2bf(o[4]) | ((unsigned int)f2bf(o[5]) << 16);
  pk.w = (unsigned int)f2bf(o[6]) | ((unsigned int)f2bf(o[7]) << 16);
  uint4 hv; hv.x = (unsigned int)s; hv.y = 0; hv.z = 0; hv.w = 0;
  unsigned short* rp = &recs[(size_t)pos * 16];
  *(uint4*)rp = pk;
  *(uint4*)(rp + 8) = hv;
}

// ---------------- wave-per-node: batched softmax + zero-padded guard-free gather ----------------
__global__ __launch_bounds__(256) void k_node(const unsigned short* __restrict__ xhb,
                                              const float* __restrict__ a_src,
                                              const float* __restrict__ a_dst,
                                              const unsigned short* __restrict__ recs,
                                              const int* __restrict__ rowptr,
                                              const float* __restrict__ bias,
                                              float* __restrict__ out, int N) {
  __shared__ float wlds[4][512];   // [wave][j*8+h], j<64
  __shared__ int   slds[4][64];
  int wv = threadIdx.x >> 6;
  int lane = threadIdx.x & 63;
  int n = blockIdx.x * 4 + wv;
  if (n >= N) return;
  int start = rowptr[n];
  int deg = rowptr[n + 1] - start;
  int jmax = (deg < 64) ? deg : 64;
  int padded = (jmax + 7) & ~7;        // multiple of 8, <= 64
  int h = lane & 7, esub = lane >> 3;
  float adst = a_dst[n * H + h];
  float asrc = a_src[n * H + h];

  // ---- phase 1a: batch record loads (16 independent loads in flight) ----
  float ae[8]; int sr[8];
#pragma unroll
  for (int it = 0; it < 8; ++it) {
    int j = it * 8 + esub;
    ae[it] = 0.f; sr[it] = 0;
    if (j < jmax) {
      const unsigned short* rp = &recs[(size_t)(start + j) * 16];
      ae[it] = bf2f(rp[h]);
      sr[it] = *(const int*)(rp + 8);
    }
  }
  // ---- phase 1b: batch a_src gathers (8 in flight) + stash src to LDS ----
  float asg[8];
#pragma unroll
  for (int it = 0; it < 8; ++it) {
    int j = it * 8 + esub;
    asg[it] = (j < jmax) ? a_src[sr[it] * H + h] : 0.f;
  }
  if (h == 0) {
#pragma unroll
    for (int it = 0; it < 8; ++it) {
      int j = it * 8 + esub;
      if (j < jmax) slds[wv][j] = sr[it];
    }
  }
  // zero-pad LDS so phase 3 needs no guards: pad src = n (valid addr), pad weight = 0
  {
    int pj = jmax + esub;               // covers up to 8 pad rows
    if (pj < padded) {
      if (h == 0) slds[wv][pj] = n;
      wlds[wv][pj * 8 + h] = 0.f;
    }
  }
  // ---- phase 1c: alphas in registers, per-lane max + raw-ae sum ----
  float al[8];
  float pmax = -1e30f, psum = 0.f;
#pragma unroll
  for (int it = 0; it < 8; ++it) {
    int j = it * 8 + esub;
    float a = -1e30f;
    if (j < jmax) {
      psum += ae[it];
      a = asg[it] + adst + ae[it];
      a = (a >= 0.f) ? a : NEG_SLOPE * a;
      pmax = fmaxf(pmax, a);
    }
    al[it] = a;
  }
  for (int j0 = 64; j0 < deg; j0 += 8) {   // overflow deg>64 (rare)
    int j = j0 + esub;
    if (j < deg) {
      const unsigned short* rp = &recs[(size_t)(start + j) * 16];
      float aev = bf2f(rp[h]);
      int src = *(const int*)(rp + 8);
      psum += aev;
      float a = a_src[src * H + h] + adst + aev;
      a = (a >= 0.f) ? a : NEG_SLOPE * a;
      pmax = fmaxf(pmax, a);
    }
  }
#pragma unroll
  for (int m = 8; m <= 32; m <<= 1) {
    pmax = fmaxf(pmax, __shfl_xor(pmax, m, 64));
    psum += __shfl_xor(psum, m, 64);
  }
  float aself = asrc + adst + psum / fmaxf((float)deg, 1.f);
  aself = (aself >= 0.f) ? aself : NEG_SLOPE * aself;
  float amax = fmaxf(pmax, aself);

  // ---- phase 2: unnormalized weights -> LDS, per-head denom ----
  float den = 0.f;
#pragma unroll
  for (int it = 0; it < 8; ++it) {
    int j = it * 8 + esub;
    if (j < jmax) {
      float wj = __expf(al[it] - amax);
      den += wj;
      wlds[wv][j * 8 + h] = wj;
    }
  }
  for (int j0 = 64; j0 < deg; j0 += 8) {   // overflow
    int j = j0 + esub;
    if (j < deg) {
      const unsigned short* rp = &recs[(size_t)(start + j) * 16];
      float aev = bf2f(rp[h]);
      int src = *(const int*)(rp + 8);
      float a = a_src[src * H + h] + adst + aev;
      a = (a >= 0.f) ? a : NEG_SLOPE * a;
      den += __expf(a - amax);
    }
  }
#pragma unroll
  for (int m = 8; m <= 32; m <<= 1) den += __shfl_xor(den, m, 64);
  float wself = __expf(aself - amax);
  float inv = 1.f / (den + wself);

  // ---- phase 3: guard-free unroll-8 gather over zero-padded lists ----
  int hc = lane >> 3;
  float inv_c  = __shfl(inv, hc, 64);
  float ws_c   = __shfl(wself, hc, 64);
  float amax_c = __shfl(amax, hc, 64);
  float adst_c = __shfl(adst, hc, 64);
  float accx, accy, accz, accw;
  {
    uint2 u = ((const uint2*)(xhb + (((size_t)n) << 8)))[lane];
    accx = ws_c * __uint_as_float(u.x << 16);
    accy = ws_c * __uint_as_float(u.x & 0xffff0000u);
    accz = ws_c * __uint_as_float(u.y << 16);
    accw = ws_c * __uint_as_float(u.y & 0xffff0000u);
  }
  for (int j0 = 0; j0 < padded; j0 += 8) {
    uint2 v[8]; float wj[8];
#pragma unroll
    for (int k = 0; k < 8; ++k) {
      wj[k] = wlds[wv][(j0 + k) * 8 + hc];
      v[k] = ((const uint2*)(xhb + (((size_t)slds[wv][j0 + k]) << 8)))[lane];
    }
#pragma unroll
    for (int k = 0; k < 8; ++k) {
      accx = fmaf(__uint_as_float(v[k].x << 16), wj[k], accx);
      accy = fmaf(__uint_as_float(v[k].x & 0xffff0000u), wj[k], accy);
      accz = fmaf(__uint_as_float(v[k].y << 16), wj[k], accz);
      accw = fmaf(__uint_as_float(v[k].y & 0xffff0000u), wj[k], accw);
    }
  }
  for (int j = 64; j < deg; ++j) {       // overflow: recompute weight
    const unsigned short* rp = &recs[(size_t)(start + j) * 16];
    float aev = bf2f(rp[hc]);
    int src = *(const int*)(rp + 8);
    float a = a_src[src * H + hc] + adst_c + aev;
    a = (a >= 0.f) ? a : NEG_SLOPE * a;
    float wj = __expf(a - amax_c);
    uint2 v = ((const uint2*)(xhb + (((size_t)src) << 8)))[lane];
    accx = fmaf(__uint_as_float(v.x << 16), wj, accx);
    accy = fmaf(__uint_as_float(v.x & 0xffff0000u), wj, accy);
    accz = fmaf(__uint_as_float(v.y << 16), wj, accz);
    accw = fmaf(__uint_as_float(v.y & 0xffff0000u), wj, accw);
  }
  accx *= inv_c; accy *= inv_c; accz *= inv_c; accw *= inv_c;

  // head mean across hc (xor 8,16,32)
#pragma unroll
  for (int m = 8; m <= 32; m <<= 1) {
    accx += __shfl_xor(accx, m, 64);
    accy += __shfl_xor(accy, m, 64);
    accz += __shfl_xor(accz, m, 64);
    accw += __shfl_xor(accw, m, 64);
  }
  if (lane < 8) {
    float4 b = ((const float4*)bias)[lane];
    float4 o;
    o.x = accx * 0.125f + b.x;
    o.y = accy * 0.125f + b.y;
    o.z = accz * 0.125f + b.z;
    o.w = accw * 0.125f + b.w;
    ((float4*)&out[(size_t)n * C])[lane] = o;
  }
}

extern "C" void kernel_launch(void* const* d_in, const int* in_sizes, int n_in,
                              void* d_out, int out_size, void* d_ws, size_t ws_size,
                              hipStream_t stream) {
  const float* x        = (const float*)d_in[0];
  const int*   ei       = (const int*)d_in[1];
  const float* ea       = (const float*)d_in[2];
  const float* W        = (const float*)d_in[3];
  const float* W_edge   = (const float*)d_in[4];
  const float* att_src  = (const float*)d_in[5];
  const float* att_dst  = (const float*)d_in[6];
  const float* att_edge = (const float*)d_in[7];
  const float* bias     = (const float*)d_in[8];
  float* out = (float*)d_out;

  int N = in_sizes[0] / FIN;
  int E = in_sizes[1] / 2;
  int nb = (N + 255) / 256;

  char* ws = (char*)d_ws;
  auto take = [&](size_t bytes) {
    char* p = ws;
    ws += (bytes + 255) & ~(size_t)255;
    return p;
  };
  unsigned short* xhb    = (unsigned short*)take((size_t)N * HC * 2);
  float*          a_src  = (float*)take((size_t)N * H * 4);
  float*          a_dst  = (float*)take((size_t)N * H * 4);
  unsigned short* recs   = (unsigned short*)take((size_t)E * 32);
  unsigned short* Whi    = (unsigned short*)take((size_t)HC * FIN * 2);
  unsigned short* Wlo    = (unsigned short*)take((size_t)HC * FIN * 2);
  int*            deg    = (int*)take((size_t)N * 4);
  int*            rowptr = (int*)take((size_t)(N + 1) * 4);
  int*            rank   = (int*)take((size_t)E * 4);
  int*            bsum   = (int*)take((size_t)nb * 4);

  hipMemsetAsync(deg, 0, (size_t)N * 4, stream);
  k_deg<<<(E + 255) / 256, 256, 0, stream>>>(ei, deg, rank, W, Whi, Wlo, E);
  k_xh<<<dim3((N + 127) / 128, 2), 256, 0, stream>>>(x, Whi, Wlo, att_src, att_dst, xhb, a_src, a_dst, N);
  k_scan1<<<nb, 256, 0, stream>>>(deg, bsum, N);
  k_scan23<<<nb, 256, 0, stream>>>(deg, bsum, rowptr, N, E, nb);
  k_edge_scatter<<<(E + 255) / 256, 256, 0, stream>>>(ei, ea, W_edge, att_edge, rowptr, rank, recs, E);
  k_node<<<(N + 3) / 4, 256, 0, stream>>>(xhb, a_src, a_dst, recs, rowptr, bias, out, N);
}